// Round 1
// baseline (145.373 us; speedup 1.0000x reference)
//
#include <hip/hip_runtime.h>

// SpikingConv2D: y = conv3x3_same(tj, W) + (1 - D_i[0,f]); out = min(y, 1.0), NHWC.
// Implicit GEMM: M = B*H*W = 100352, N = F = 128, K = C*9 = 1152 (9 taps x 4 chunks of 32).
// bf16 MFMA 16x16x32, 128x128 tile, 4 waves, 4x4 frags/wave.

#define BZ 32
#define CC 128
#define HH 56
#define WWD 56
#define HWP (HH * WWD)   // 3136
#define FF 128
#define KT 9
#define MTOT (BZ * HWP)  // 100352
#define BM 128
#define BN 128
#define BK 32

typedef __attribute__((ext_vector_type(8))) __bf16 bf16x8;
typedef __attribute__((ext_vector_type(4))) float f32x4;
typedef __attribute__((ext_vector_type(8))) unsigned short us8;

__device__ __forceinline__ unsigned short f2bf(float f) {
  unsigned int u = __float_as_uint(f);
  unsigned int r = (u + 0x7FFFu + ((u >> 16) & 1u)) >> 16;
  return (unsigned short)r;
}

// Repack W [k=c*9+r][f] fp32 -> Wt[r][f][c] bf16 so GEMM B-staging is contiguous in c.
__global__ void prep_w_kernel(const float* __restrict__ W, unsigned short* __restrict__ Wt) {
  int idx = blockIdx.x * 256 + threadIdx.x;
  if (idx >= KT * FF * CC) return;
  int r = idx >> 14;        // / (128*128)
  int rem = idx & 16383;
  int f = rem >> 7;
  int c = rem & 127;
  Wt[idx] = f2bf(W[(c * KT + r) * FF + f]);
}

__global__ __launch_bounds__(256) void spiking_conv_kernel(
    const float* __restrict__ x, const unsigned short* __restrict__ Wt,
    const float* __restrict__ Wf, const float* __restrict__ Di,
    float* __restrict__ out, int useWt) {
  __shared__ unsigned short Asm[BM][BK];  // [pixel][k]  8 KB
  __shared__ unsigned short Bsm[BN][BK];  // [filter][k] 8 KB (B transposed for b128 frag reads)

  const int tid = threadIdx.x;
  const int m0 = blockIdx.x * BM;

  // --- staging coords (fixed per thread) ---
  const int mi = tid & 127;   // pixel row of tile (also filter row for B-staging)
  const int half = tid >> 7;  // which 16-channel half this thread stages
  const int m = m0 + mi;
  const int bimg = m / HWP;
  const int p = m - bimg * HWP;
  const int h = p / WWD;
  const int w = p - h * WWD;
  const int baseA = (bimg * CC) * HWP + h * WWD + w;

  // --- fragment coords ---
  const int lane = tid & 63;
  const int wid = tid >> 6;
  const int wr = wid >> 1;   // wave row (0..1) -> 64 output rows
  const int wc = wid & 1;    // wave col (0..1) -> 64 output cols
  const int frow = lane & 15;
  const int kg = lane >> 4;  // k-group: elements kg*8 .. kg*8+7

  f32x4 acc[4][4];
  const f32x4 zero = {0.0f, 0.0f, 0.0f, 0.0f};
#pragma unroll
  for (int i = 0; i < 4; ++i)
#pragma unroll
    for (int j = 0; j < 4; ++j) acc[i][j] = zero;

  for (int r = 0; r < KT; ++r) {
    const int dh = r / 3 - 1;
    const int dw = r - (r / 3) * 3 - 1;
    const int hh = h + dh;
    const int ww2 = w + dw;
    const bool valid = ((unsigned)hh < (unsigned)HH) && ((unsigned)ww2 < (unsigned)WWD);
    const int aoff = baseA + dh * WWD + dw + half * 16 * HWP;

    for (int c0 = 0; c0 < CC; c0 += BK) {
      __syncthreads();  // previous iteration's frag reads done before overwrite
      // ---- stage A: 16 channels of one pixel per thread ----
      {
        const float* src = x + aoff + c0 * HWP;
        us8 v0, v1;
#pragma unroll
        for (int i = 0; i < 8; ++i) {
          float f0 = valid ? src[i * HWP] : 0.0f;
          float f1 = valid ? src[(i + 8) * HWP] : 0.0f;
          v0[i] = f2bf(f0);
          v1[i] = f2bf(f1);
        }
        *reinterpret_cast<us8*>(&Asm[mi][half * 16]) = v0;
        *reinterpret_cast<us8*>(&Asm[mi][half * 16 + 8]) = v1;
      }
      // ---- stage B: 16 channels of one filter per thread ----
      if (useWt) {
        const unsigned short* src = Wt + (r * FF + mi) * CC + c0 + half * 16;
        us8 v0 = *reinterpret_cast<const us8*>(src);
        us8 v1 = *reinterpret_cast<const us8*>(src + 8);
        *reinterpret_cast<us8*>(&Bsm[mi][half * 16]) = v0;
        *reinterpret_cast<us8*>(&Bsm[mi][half * 16 + 8]) = v1;
      } else {
        us8 v0, v1;
#pragma unroll
        for (int i = 0; i < 8; ++i) {
          int c = c0 + half * 16 + i;
          v0[i] = f2bf(Wf[(c * KT + r) * FF + mi]);
          v1[i] = f2bf(Wf[((c + 8) * KT + r) * FF + mi]);
        }
        *reinterpret_cast<us8*>(&Bsm[mi][half * 16]) = v0;
        *reinterpret_cast<us8*>(&Bsm[mi][half * 16 + 8]) = v1;
      }
      __syncthreads();

      // ---- fragments + MFMA ----
      bf16x8 af[4], bfr[4];
#pragma unroll
      for (int i = 0; i < 4; ++i)
        af[i] = *reinterpret_cast<const bf16x8*>(&Asm[wr * 64 + i * 16 + frow][kg * 8]);
#pragma unroll
      for (int j = 0; j < 4; ++j)
        bfr[j] = *reinterpret_cast<const bf16x8*>(&Bsm[wc * 64 + j * 16 + frow][kg * 8]);
#pragma unroll
      for (int i = 0; i < 4; ++i)
#pragma unroll
        for (int j = 0; j < 4; ++j)
          acc[i][j] = __builtin_amdgcn_mfma_f32_16x16x32_bf16(af[i], bfr[j], acc[i][j], 0, 0, 0);
    }
  }

  // ---- epilogue: + (T_MAX - T_MIN - D_i[f]) + T_MIN, clamp at T_MAX ----
#pragma unroll
  for (int j = 0; j < 4; ++j) {
    const int col = wc * 64 + j * 16 + frow;  // filter index
    const float thr = 1.0f - Di[col];         // T_MAX - T_MIN - D_i[0,f]
#pragma unroll
    for (int i = 0; i < 4; ++i) {
      const int rbase = m0 + wr * 64 + i * 16 + kg * 4;
#pragma unroll
      for (int q = 0; q < 4; ++q) {
        float v = acc[i][j][q] + thr;  // + T_MIN (= 0)
        out[(size_t)(rbase + q) * FF + col] = fminf(v, 1.0f);
      }
    }
  }
}

extern "C" void kernel_launch(void* const* d_in, const int* in_sizes, int n_in,
                              void* d_out, int out_size, void* d_ws, size_t ws_size,
                              hipStream_t stream) {
  const float* tj = (const float*)d_in[0];
  const float* W = (const float*)d_in[1];
  const float* Di = (const float*)d_in[2];
  float* out = (float*)d_out;
  unsigned short* Wt = (unsigned short*)d_ws;

  const int useWt = (ws_size >= (size_t)(KT * FF * CC * 2)) ? 1 : 0;
  if (useWt) {
    prep_w_kernel<<<(KT * FF * CC + 255) / 256, 256, 0, stream>>>(W, Wt);
  }
  spiking_conv_kernel<<<MTOT / BM, 256, 0, stream>>>(tj, Wt, W, Di, out, useWt);
}

// Round 2
// 66.148 us; speedup vs baseline: 2.1977x; 2.1977x over previous
//
#include <hip/hip_runtime.h>

// SpikingConv2D: y = conv3x3_same(tj, W) + (1 - D_i[0,f]); out = min(y, 1.0), NHWC fp32.
// Two-pass: (1) pad+convert NCHW f32 -> NHWC bf16 [32,58,58,128] in ws; W -> swizzled bf16.
//           (2) implicit GEMM, per-tap BK=128, global_load_lds(16B), T2 XOR-swizzle via
//               pre-swizzled global source (linear LDS dest), 64 MFMA / barrier-pair.

#define BZ 32
#define CC 128
#define HH 56
#define WWD 56
#define HWP 3136
#define FF 128
#define KT 9
#define PH 58
#define PW 58
#define MTOT 100352
#define BM 128

typedef __attribute__((ext_vector_type(8))) __bf16 bf16x8;
typedef __attribute__((ext_vector_type(4))) float f32x4;
typedef __attribute__((ext_vector_type(8))) unsigned short us8;
typedef __attribute__((ext_vector_type(4))) float flt4;

__device__ __forceinline__ unsigned short f2bf(float f) {
  unsigned int u = __float_as_uint(f);
  unsigned int r = (u + 0x7FFFu + ((u >> 16) & 1u)) >> 16;
  return (unsigned short)r;
}

#define GLOAD_LDS16(g, l)                                                              \
  __builtin_amdgcn_global_load_lds((const __attribute__((address_space(1))) void*)(g), \
                                   (__attribute__((address_space(3))) void*)(l), 16, 0, 0)

// ---- W repack: [k=c*9+r][f] fp32 -> Wt[r][f][c'] bf16, c' optionally XOR-swizzled ----
__global__ void prep_w_kernel(const float* __restrict__ W, unsigned short* __restrict__ Wt,
                              int swz) {
  int idx = blockIdx.x * 256 + threadIdx.x;
  if (idx >= KT * FF * CC) return;
  int r = idx >> 14;
  int rem = idx & 16383;
  int f = rem >> 7;
  int c = rem & 127;
  int cs = swz ? (c ^ ((f & 7) << 3)) : c;
  Wt[(r * FF + f) * CC + cs] = f2bf(W[(c * KT + r) * FF + f]);
}

// ---- image prepass: x NCHW f32 -> xp padded NHWC bf16 [B][58][58][128] ----
__global__ __launch_bounds__(256) void prep_x_kernel(const float* __restrict__ x,
                                                     unsigned short* __restrict__ xp) {
  const int blk = blockIdx.x;      // B*58 blocks; one padded row each
  const int b = blk / PH;
  const int ph = blk - b * PH;
  const int tid = threadIdx.x;
  unsigned short* dst = xp + (size_t)(b * PH + ph) * PW * CC;

  if (ph == 0 || ph == PH - 1) {   // zero border row: 58*128 elems = 928 us8 chunks
    us8 z;
#pragma unroll
    for (int k = 0; k < 8; ++k) z[k] = 0;
    for (int i = tid; i < PW * CC / 8; i += 256) reinterpret_cast<us8*>(dst)[i] = z;
    return;
  }

  __shared__ float sm[CC][57];
  const int h = ph - 1;
  {  // load 128 channel-rows of 56 floats, coalesced (2 threads per channel)
    const int c = tid >> 1;
    const int half = tid & 1;
    const float* src = x + ((size_t)(b * CC + c)) * HWP + h * WWD + half * 28;
#pragma unroll
    for (int k = 0; k < 7; ++k) {
      flt4 v = *reinterpret_cast<const flt4*>(src + k * 4);
      sm[c][half * 28 + k * 4 + 0] = v[0];
      sm[c][half * 28 + k * 4 + 1] = v[1];
      sm[c][half * 28 + k * 4 + 2] = v[2];
      sm[c][half * 28 + k * 4 + 3] = v[3];
    }
  }
  __syncthreads();
  // write NHWC bf16: 58 pixels * 16 chunks of 8 ch
  for (int i = tid; i < PW * 16; i += 256) {
    const int ww = i >> 4;
    const int cg = i & 15;
    us8 v;
    if (ww == 0 || ww == PW - 1) {
#pragma unroll
      for (int k = 0; k < 8; ++k) v[k] = 0;
    } else {
      const int w = ww - 1;
#pragma unroll
      for (int k = 0; k < 8; ++k) v[k] = f2bf(sm[cg * 8 + k][w]);
    }
    reinterpret_cast<us8*>(dst)[i] = v;
  }
}

// ---- main implicit-GEMM conv kernel (fast path) ----
__global__ __launch_bounds__(256, 2) void spiking_conv_main(
    const unsigned short* __restrict__ xp, const unsigned short* __restrict__ Wt,
    const float* __restrict__ Di, float* __restrict__ out) {
  __shared__ unsigned short Asm[BM * CC];  // 32 KB, linear dest, swizzled content
  __shared__ unsigned short Bsm[FF * CC];  // 32 KB

  // XCD-aware bijective swizzle: 784 blocks = 98 per XCD
  const int bid = blockIdx.x;
  const int wg = (bid & 7) * 98 + (bid >> 3);
  const int m0 = wg * BM;

  const int tid = threadIdx.x;
  const int lane = tid & 63;
  const int wv = tid >> 6;
  const int wr = wv >> 1, wc = wv & 1;
  const int frow = lane & 15, kg = lane >> 4;

  // --- precompute per-thread staging source offsets (elements) ---
  int aoff[8];
#pragma unroll
  for (int t = 0; t < 8; ++t) {
    const int row = wv * 32 + t * 4 + (lane >> 4);
    const int m = m0 + row;
    const int b = m / HWP;
    const int p = m - b * HWP;
    const int h = p / WWD;
    const int w = p - h * WWD;
    const int chunk = (lane & 15) ^ (row & 7);  // inverse-swizzled source chunk
    aoff[t] = ((b * PH + h + 1) * PW + (w + 1)) * CC + chunk * 8;
  }
  const unsigned short* wsrc = Wt + wv * 4096 + lane * 8;

  f32x4 acc[4][4];
  const f32x4 zero = {0.0f, 0.0f, 0.0f, 0.0f};
#pragma unroll
  for (int i = 0; i < 4; ++i)
#pragma unroll
    for (int j = 0; j < 4; ++j) acc[i][j] = zero;

  for (int r = 0; r < KT; ++r) {
    const int dh = r / 3 - 1;
    const int dw = r - (r / 3) * 3 - 1;
    const int tapoff = (dh * PW + dw) * CC;
    __syncthreads();  // prior frag reads done before overwrite
#pragma unroll
    for (int t = 0; t < 8; ++t)
      GLOAD_LDS16(xp + aoff[t] + tapoff, Asm + wv * 4096 + t * 512);
#pragma unroll
    for (int t = 0; t < 8; ++t)
      GLOAD_LDS16(wsrc + r * (FF * CC) + t * 512, Bsm + wv * 4096 + t * 512);
    __syncthreads();  // includes vmcnt(0) drain

#pragma unroll
    for (int kk = 0; kk < 4; ++kk) {
      bf16x8 af[4], bfr[4];
#pragma unroll
      for (int i = 0; i < 4; ++i) {
        const int rowA = wr * 64 + i * 16 + frow;
        const int colb = (kk * 64 + kg * 16) ^ ((rowA & 7) << 4);
        af[i] = *reinterpret_cast<const bf16x8*>(
            reinterpret_cast<const char*>(Asm) + rowA * 256 + colb);
      }
#pragma unroll
      for (int j = 0; j < 4; ++j) {
        const int rowB = wc * 64 + j * 16 + frow;
        const int colb = (kk * 64 + kg * 16) ^ ((rowB & 7) << 4);
        bfr[j] = *reinterpret_cast<const bf16x8*>(
            reinterpret_cast<const char*>(Bsm) + rowB * 256 + colb);
      }
#pragma unroll
      for (int i = 0; i < 4; ++i)
#pragma unroll
        for (int j = 0; j < 4; ++j)
          acc[i][j] = __builtin_amdgcn_mfma_f32_16x16x32_bf16(af[i], bfr[j], acc[i][j], 0, 0, 0);
    }
  }

  // ---- epilogue: + (1 - D_i[f]), clamp 1.0, NHWC fp32 ----
#pragma unroll
  for (int j = 0; j < 4; ++j) {
    const int col = wc * 64 + j * 16 + frow;
    const float thr = 1.0f - Di[col];
#pragma unroll
    for (int i = 0; i < 4; ++i) {
      const int rbase = m0 + wr * 64 + i * 16 + kg * 4;
#pragma unroll
      for (int q = 0; q < 4; ++q) {
        float v = acc[i][j][q] + thr;
        out[(size_t)(rbase + q) * FF + col] = fminf(v, 1.0f);
      }
    }
  }
}

// ---- fallback (round-0 kernel) for small workspace ----
__global__ __launch_bounds__(256) void spiking_conv_fallback(
    const float* __restrict__ x, const unsigned short* __restrict__ Wt,
    const float* __restrict__ Wf, const float* __restrict__ Di,
    float* __restrict__ out, int useWt) {
  __shared__ unsigned short Asm2[BM][32];
  __shared__ unsigned short Bsm2[FF][32];
  const int tid = threadIdx.x;
  const int m0 = blockIdx.x * BM;
  const int mi = tid & 127;
  const int half = tid >> 7;
  const int m = m0 + mi;
  const int bimg = m / HWP;
  const int p = m - bimg * HWP;
  const int h = p / WWD;
  const int w = p - h * WWD;
  const int baseA = (bimg * CC) * HWP + h * WWD + w;
  const int lane = tid & 63;
  const int wid = tid >> 6;
  const int wr = wid >> 1;
  const int wc = wid & 1;
  const int frow = lane & 15;
  const int kg = lane >> 4;
  f32x4 acc[4][4];
  const f32x4 zero = {0.0f, 0.0f, 0.0f, 0.0f};
#pragma unroll
  for (int i = 0; i < 4; ++i)
#pragma unroll
    for (int j = 0; j < 4; ++j) acc[i][j] = zero;
  for (int r = 0; r < KT; ++r) {
    const int dh = r / 3 - 1;
    const int dw = r - (r / 3) * 3 - 1;
    const int hh = h + dh;
    const int ww2 = w + dw;
    const bool valid = ((unsigned)hh < (unsigned)HH) && ((unsigned)ww2 < (unsigned)WWD);
    const int aoff2 = baseA + dh * WWD + dw + half * 16 * HWP;
    for (int c0 = 0; c0 < CC; c0 += 32) {
      __syncthreads();
      {
        const float* src = x + aoff2 + c0 * HWP;
        us8 v0, v1;
#pragma unroll
        for (int i = 0; i < 8; ++i) {
          float f0 = valid ? src[i * HWP] : 0.0f;
          float f1 = valid ? src[(i + 8) * HWP] : 0.0f;
          v0[i] = f2bf(f0);
          v1[i] = f2bf(f1);
        }
        *reinterpret_cast<us8*>(&Asm2[mi][half * 16]) = v0;
        *reinterpret_cast<us8*>(&Asm2[mi][half * 16 + 8]) = v1;
      }
      if (useWt) {
        const unsigned short* src = Wt + (r * FF + mi) * CC + c0 + half * 16;
        *reinterpret_cast<us8*>(&Bsm2[mi][half * 16]) = *reinterpret_cast<const us8*>(src);
        *reinterpret_cast<us8*>(&Bsm2[mi][half * 16 + 8]) = *reinterpret_cast<const us8*>(src + 8);
      } else {
        us8 v0, v1;
#pragma unroll
        for (int i = 0; i < 8; ++i) {
          int c = c0 + half * 16 + i;
          v0[i] = f2bf(Wf[(c * KT + r) * FF + mi]);
          v1[i] = f2bf(Wf[((c + 8) * KT + r) * FF + mi]);
        }
        *reinterpret_cast<us8*>(&Bsm2[mi][half * 16]) = v0;
        *reinterpret_cast<us8*>(&Bsm2[mi][half * 16 + 8]) = v1;
      }
      __syncthreads();
      bf16x8 af[4], bfr[4];
#pragma unroll
      for (int i = 0; i < 4; ++i)
        af[i] = *reinterpret_cast<const bf16x8*>(&Asm2[wr * 64 + i * 16 + frow][kg * 8]);
#pragma unroll
      for (int j = 0; j < 4; ++j)
        bfr[j] = *reinterpret_cast<const bf16x8*>(&Bsm2[wc * 64 + j * 16 + frow][kg * 8]);
#pragma unroll
      for (int i = 0; i < 4; ++i)
#pragma unroll
        for (int j = 0; j < 4; ++j)
          acc[i][j] = __builtin_amdgcn_mfma_f32_16x16x32_bf16(af[i], bfr[j], acc[i][j], 0, 0, 0);
    }
  }
#pragma unroll
  for (int j = 0; j < 4; ++j) {
    const int col = wc * 64 + j * 16 + frow;
    const float thr = 1.0f - Di[col];
#pragma unroll
    for (int i = 0; i < 4; ++i) {
      const int rbase = m0 + wr * 64 + i * 16 + kg * 4;
#pragma unroll
      for (int q = 0; q < 4; ++q) {
        float v = acc[i][j][q] + thr;
        out[(size_t)(rbase + q) * FF + col] = fminf(v, 1.0f);
      }
    }
  }
}

extern "C" void kernel_launch(void* const* d_in, const int* in_sizes, int n_in,
                              void* d_out, int out_size, void* d_ws, size_t ws_size,
                              hipStream_t stream) {
  const float* tj = (const float*)d_in[0];
  const float* W = (const float*)d_in[1];
  const float* Di = (const float*)d_in[2];
  float* out = (float*)d_out;

  const size_t wt_bytes = (size_t)KT * FF * CC * 2;               // 294912
  const size_t xp_bytes = (size_t)BZ * PH * PW * CC * 2;          // 27557888
  unsigned short* Wt = (unsigned short*)d_ws;
  unsigned short* xp = (unsigned short*)((char*)d_ws + wt_bytes);

  if (ws_size >= wt_bytes + xp_bytes) {
    prep_w_kernel<<<(KT * FF * CC + 255) / 256, 256, 0, stream>>>(W, Wt, 1);
    prep_x_kernel<<<BZ * PH, 256, 0, stream>>>(tj, xp);
    spiking_conv_main<<<MTOT / BM, 256, 0, stream>>>(xp, Wt, Di, out);
  } else {
    const int useWt = (ws_size >= wt_bytes) ? 1 : 0;
    if (useWt) prep_w_kernel<<<(KT * FF * CC + 255) / 256, 256, 0, stream>>>(W, Wt, 0);
    spiking_conv_fallback<<<MTOT / BM, 256, 0, stream>>>(tj, Wt, W, Di, out, useWt);
  }
}

// Round 3
// 58.401 us; speedup vs baseline: 2.4892x; 1.1327x over previous
//
#include <hip/hip_runtime.h>

// SpikingConv2D: y = conv3x3_same(tj, W) + (1 - D_i[0,f]); out = min(y, 1.0), NHWC fp32.
// R2: patch-resident implicit GEMM. Block = 8 rows x 56 cols = 448 pixels, 8 waves.
// K = 1152 split into 36 steps (9 taps x 4 channel-quarters of 32). Patch quarter +
// B tile double-buffered, counted vmcnt (never 0 in loop), raw s_barrier, granule
// XOR-swizzle (g ^= (g>>3)&7) on both staging-source and read side.

#define BZ 32
#define CC 128
#define HH 56
#define WWD 56
#define HWP 3136
#define FF 128
#define PH 58
#define PW 58
#define QC 32
#define PATCH_G 2320     // 10*58*4 real granules
#define PATCH_BYTES 40960  // padded to 2560 granules
#define BQ_OFF 81920
#define BQ_BYTES 8192
#define LDS_TOTAL 98304
#define NSTEP 36

typedef __attribute__((ext_vector_type(8))) __bf16 bf16x8;
typedef __attribute__((ext_vector_type(4))) float f32x4;
typedef __attribute__((ext_vector_type(8))) unsigned short us8;
typedef __attribute__((ext_vector_type(4))) float flt4;

__device__ __forceinline__ unsigned short f2bf(float f) {
  unsigned int u = __float_as_uint(f);
  unsigned int r = (u + 0x7FFFu + ((u >> 16) & 1u)) >> 16;
  return (unsigned short)r;
}

#define GLOAD_LDS16(g, l)                                                              \
  __builtin_amdgcn_global_load_lds((const __attribute__((address_space(1))) void*)(g), \
                                   (__attribute__((address_space(3))) void*)(l), 16, 0, 0)

// ---- W repack: W[(c*9+r)][f] f32 -> Wt granules: pos (q*9+r)*512 + g', g'=g^((g>>3)&7),
//      granule g = f*4+kg holds channels q*32+kg*8 .. +8 of filter f, tap r. ----
__global__ void prep_w_kernel(const float* __restrict__ W, unsigned short* __restrict__ Wt) {
  int idx = blockIdx.x * 256 + threadIdx.x;
  if (idx >= 4 * 9 * 512) return;
  int qr = idx >> 9;
  int gp = idx & 511;
  int g = gp ^ ((gp >> 3) & 7);
  int q = qr / 9, r = qr - q * 9;
  int f = g >> 2, kg = g & 3;
  us8 v;
#pragma unroll
  for (int j = 0; j < 8; ++j) {
    int c = q * QC + kg * 8 + j;
    v[j] = f2bf(W[(c * 9 + r) * FF + f]);
  }
  *reinterpret_cast<us8*>(Wt + (size_t)idx * 8) = v;
}

// ---- image prepass: x NCHW f32 -> xp padded NHWC bf16 [B][58][58][128] ----
__global__ __launch_bounds__(256) void prep_x_kernel(const float* __restrict__ x,
                                                     unsigned short* __restrict__ xp) {
  const int blk = blockIdx.x;
  const int b = blk / PH;
  const int ph = blk - b * PH;
  const int tid = threadIdx.x;
  unsigned short* dst = xp + (size_t)(b * PH + ph) * PW * CC;

  if (ph == 0 || ph == PH - 1) {
    us8 z;
#pragma unroll
    for (int k = 0; k < 8; ++k) z[k] = 0;
    for (int i = tid; i < PW * CC / 8; i += 256) reinterpret_cast<us8*>(dst)[i] = z;
    return;
  }

  __shared__ float sm[CC][57];
  const int h = ph - 1;
  {
    const int c = tid >> 1;
    const int half = tid & 1;
    const float* src = x + ((size_t)(b * CC + c)) * HWP + h * WWD + half * 28;
#pragma unroll
    for (int k = 0; k < 7; ++k) {
      flt4 v = *reinterpret_cast<const flt4*>(src + k * 4);
      sm[c][half * 28 + k * 4 + 0] = v[0];
      sm[c][half * 28 + k * 4 + 1] = v[1];
      sm[c][half * 28 + k * 4 + 2] = v[2];
      sm[c][half * 28 + k * 4 + 3] = v[3];
    }
  }
  __syncthreads();
  for (int i = tid; i < PW * 16; i += 256) {
    const int ww = i >> 4;
    const int cg = i & 15;
    us8 v;
    if (ww == 0 || ww == PW - 1) {
#pragma unroll
      for (int k = 0; k < 8; ++k) v[k] = 0;
    } else {
      const int w = ww - 1;
#pragma unroll
      for (int k = 0; k < 8; ++k) v[k] = f2bf(sm[cg * 8 + k][w]);
    }
    reinterpret_cast<us8*>(dst)[i] = v;
  }
}

// ---------------- main kernel ----------------
struct Ctx {
  const unsigned short* xp;
  const unsigned short* Wt;
  int tid;
  int srcA[5];    // xp element offsets per staging chunk (quarter 0 base)
  int gbase[7];   // A-frag granule (dh=dw=0) per M-frag
  int bOffB[4];   // B-frag swizzled byte offsets
  f32x4 acc[7][4];
};

template <int S>
__device__ __forceinline__ void step(Ctx& c, unsigned char* lds) {
  constexpr int q = S / 9, r = S - q * 9;
  constexpr int dh = r / 3 - 1, dw = r - (r / 3) * 3 - 1;
  constexpr int tapoff = dh * 232 + dw * 4;  // granules (row stride 58*4)
  constexpr bool issueA = (r < 5) && (q < 3);
  constexpr bool issueB = (S < NSTEP - 1);
  constexpr int nIssue = (issueA ? 1 : 0) + (issueB ? 1 : 0);

  if constexpr (issueA) {
    const unsigned short* src = c.xp + c.srcA[r] + (q + 1) * QC;
    unsigned char* dst = lds + ((q + 1) & 1) * PATCH_BYTES + (size_t)(r * 512 + c.tid) * 16;
    GLOAD_LDS16(src, dst);
  }
  if constexpr (issueB) {
    const unsigned short* src = c.Wt + (size_t)(S + 1) * 4096 + c.tid * 8;
    unsigned char* dst = lds + BQ_OFF + ((S + 1) & 1) * BQ_BYTES + (size_t)c.tid * 16;
    GLOAD_LDS16(src, dst);
  }
  asm volatile("s_waitcnt vmcnt(%0)" ::"n"(nIssue));
  __builtin_amdgcn_s_barrier();
  __builtin_amdgcn_sched_barrier(0);

  const unsigned char* pa = lds + (q & 1) * PATCH_BYTES;
  const unsigned char* pb = lds + BQ_OFF + (S & 1) * BQ_BYTES;
  bf16x8 af[7], bf[4];
#pragma unroll
  for (int i = 0; i < 7; ++i) {
    int g = c.gbase[i] + tapoff;
    int ga = (g ^ ((g >> 3) & 7)) << 4;
    af[i] = *reinterpret_cast<const bf16x8*>(pa + ga);
  }
#pragma unroll
  for (int j = 0; j < 4; ++j)
    bf[j] = *reinterpret_cast<const bf16x8*>(pb + c.bOffB[j]);

  __builtin_amdgcn_s_setprio(1);
#pragma unroll
  for (int i = 0; i < 7; ++i)
#pragma unroll
    for (int j = 0; j < 4; ++j)
      c.acc[i][j] = __builtin_amdgcn_mfma_f32_16x16x32_bf16(af[i], bf[j], c.acc[i][j], 0, 0, 0);
  __builtin_amdgcn_s_setprio(0);
  __builtin_amdgcn_sched_barrier(0);
  __builtin_amdgcn_s_barrier();
}

template <int S>
__device__ __forceinline__ void do_steps(Ctx& c, unsigned char* lds) {
  step<S>(c, lds);
  if constexpr (S + 1 < NSTEP) do_steps<S + 1>(c, lds);
}

__global__ __launch_bounds__(512, 2) void spiking_conv_main(
    const unsigned short* __restrict__ xp, const unsigned short* __restrict__ Wt,
    const float* __restrict__ Di, float* __restrict__ out) {
  extern __shared__ unsigned char lds[];

  const int bid = blockIdx.x;
  const int wg = (bid & 7) * 28 + (bid >> 3);  // 224 = 28 per XCD, bijective
  const int b = wg / 7;
  const int ht = wg - b * 7;
  const int h0 = ht * 8;

  Ctx c;
  c.xp = xp;
  c.Wt = Wt;
  const int tid = threadIdx.x;
  c.tid = tid;
  const int lane = tid & 63, wv = tid >> 6;
  const int wr = wv >> 1, wc = wv & 1;
  const int frow = lane & 15, kg = lane >> 4;

#pragma unroll
  for (int k = 0; k < 5; ++k) {
    int gp = k * 512 + tid;
    int g = gp ^ ((gp >> 3) & 7);
    int ph = g / 232;
    int rem = g - ph * 232;
    int pw = rem >> 2;
    int kg2 = rem & 3;
    int e = ((b * PH + h0 + ph) * PW + pw) * CC + kg2 * 8;
    c.srcA[k] = (gp < PATCH_G) ? e : 0;
  }
#pragma unroll
  for (int i = 0; i < 7; ++i) {
    int t = 16 * i + frow;
    int hl = (t >= 56) ? 1 : 0;
    int wl = t - 56 * hl;
    c.gbase[i] = ((2 * wr + hl + 1) * 58 + (wl + 1)) * 4 + kg;
  }
#pragma unroll
  for (int j = 0; j < 4; ++j) {
    int gB = (wc * 64 + 16 * j + frow) * 4 + kg;
    c.bOffB[j] = (gB ^ ((gB >> 3) & 7)) << 4;
  }
  const f32x4 zero = {0.0f, 0.0f, 0.0f, 0.0f};
#pragma unroll
  for (int i = 0; i < 7; ++i)
#pragma unroll
    for (int j = 0; j < 4; ++j) c.acc[i][j] = zero;

  // prologue: stage patch quarter 0 (parity 0) + B step 0 (parity 0)
#pragma unroll
  for (int k = 0; k < 5; ++k)
    GLOAD_LDS16(xp + c.srcA[k], lds + (size_t)(k * 512 + tid) * 16);
  GLOAD_LDS16(Wt + tid * 8, lds + BQ_OFF + (size_t)tid * 16);
  asm volatile("s_waitcnt vmcnt(0)");
  __builtin_amdgcn_s_barrier();
  __builtin_amdgcn_sched_barrier(0);

  do_steps<0>(c, lds);

  // epilogue: + (1 - D_i[f]), clamp 1.0, NHWC fp32
#pragma unroll
  for (int j = 0; j < 4; ++j) {
    const int col = wc * 64 + 16 * j + frow;
    const float thr = 1.0f - Di[col];
#pragma unroll
    for (int i = 0; i < 7; ++i) {
      const int bt = 16 * i + kg * 4;          // run of 4 never crosses a 56-boundary
      const int hl = (bt >= 56) ? 1 : 0;
      const int wl0 = bt - 56 * hl;
      const int orow = h0 + 2 * wr + hl;
      const size_t obase = ((size_t)b * HWP + (size_t)orow * WWD + wl0) * FF + col;
#pragma unroll
      for (int qq = 0; qq < 4; ++qq) {
        float v = c.acc[i][j][qq] + thr;
        out[obase + (size_t)qq * FF] = fminf(v, 1.0f);
      }
    }
  }
}

// ---- fallback (round-0 style, reads W directly) ----
__global__ __launch_bounds__(256) void spiking_conv_fallback(
    const float* __restrict__ x, const float* __restrict__ Wf,
    const float* __restrict__ Di, float* __restrict__ out) {
  __shared__ unsigned short Asm2[128][32];
  __shared__ unsigned short Bsm2[128][32];
  const int tid = threadIdx.x;
  const int m0 = blockIdx.x * 128;
  const int mi = tid & 127;
  const int half = tid >> 7;
  const int m = m0 + mi;
  const int bimg = m / HWP;
  const int p = m - bimg * HWP;
  const int h = p / WWD;
  const int w = p - h * WWD;
  const int baseA = (bimg * CC) * HWP + h * WWD + w;
  const int lane = tid & 63;
  const int wid = tid >> 6;
  const int wr = wid >> 1;
  const int wc = wid & 1;
  const int frow = lane & 15;
  const int kg = lane >> 4;
  f32x4 acc[4][4];
  const f32x4 zero = {0.0f, 0.0f, 0.0f, 0.0f};
#pragma unroll
  for (int i = 0; i < 4; ++i)
#pragma unroll
    for (int j = 0; j < 4; ++j) acc[i][j] = zero;
  for (int r = 0; r < 9; ++r) {
    const int dh = r / 3 - 1;
    const int dw = r - (r / 3) * 3 - 1;
    const int hh = h + dh;
    const int ww2 = w + dw;
    const bool valid = ((unsigned)hh < (unsigned)HH) && ((unsigned)ww2 < (unsigned)WWD);
    const int aoff2 = baseA + dh * WWD + dw + half * 16 * HWP;
    for (int c0 = 0; c0 < CC; c0 += 32) {
      __syncthreads();
      {
        const float* src = x + aoff2 + c0 * HWP;
        us8 v0, v1;
#pragma unroll
        for (int i = 0; i < 8; ++i) {
          float f0 = valid ? src[i * HWP] : 0.0f;
          float f1 = valid ? src[(i + 8) * HWP] : 0.0f;
          v0[i] = f2bf(f0);
          v1[i] = f2bf(f1);
        }
        *reinterpret_cast<us8*>(&Asm2[mi][half * 16]) = v0;
        *reinterpret_cast<us8*>(&Asm2[mi][half * 16 + 8]) = v1;
      }
      {
        us8 v0, v1;
#pragma unroll
        for (int i = 0; i < 8; ++i) {
          int cc2 = c0 + half * 16 + i;
          v0[i] = f2bf(Wf[(cc2 * 9 + r) * FF + mi]);
          v1[i] = f2bf(Wf[((cc2 + 8) * 9 + r) * FF + mi]);
        }
        *reinterpret_cast<us8*>(&Bsm2[mi][half * 16]) = v0;
        *reinterpret_cast<us8*>(&Bsm2[mi][half * 16 + 8]) = v1;
      }
      __syncthreads();
      bf16x8 af[4], bfr[4];
#pragma unroll
      for (int i = 0; i < 4; ++i)
        af[i] = *reinterpret_cast<const bf16x8*>(&Asm2[wr * 64 + i * 16 + frow][kg * 8]);
#pragma unroll
      for (int j = 0; j < 4; ++j)
        bfr[j] = *reinterpret_cast<const bf16x8*>(&Bsm2[wc * 64 + j * 16 + frow][kg * 8]);
#pragma unroll
      for (int i = 0; i < 4; ++i)
#pragma unroll
        for (int j = 0; j < 4; ++j)
          acc[i][j] = __builtin_amdgcn_mfma_f32_16x16x32_bf16(af[i], bfr[j], acc[i][j], 0, 0, 0);
    }
  }
#pragma unroll
  for (int j = 0; j < 4; ++j) {
    const int col = wc * 64 + j * 16 + frow;
    const float thr = 1.0f - Di[col];
#pragma unroll
    for (int i = 0; i < 4; ++i) {
      const int rbase = m0 + wr * 64 + i * 16 + kg * 4;
#pragma unroll
      for (int qq = 0; qq < 4; ++qq) {
        float v = acc[i][j][qq] + thr;
        out[(size_t)(rbase + qq) * FF + col] = fminf(v, 1.0f);
      }
    }
  }
}

extern "C" void kernel_launch(void* const* d_in, const int* in_sizes, int n_in,
                              void* d_out, int out_size, void* d_ws, size_t ws_size,
                              hipStream_t stream) {
  const float* tj = (const float*)d_in[0];
  const float* W = (const float*)d_in[1];
  const float* Di = (const float*)d_in[2];
  float* out = (float*)d_out;

  const size_t wt_bytes = (size_t)4 * 9 * 512 * 16;        // 294912
  const size_t xp_bytes = (size_t)BZ * PH * PW * CC * 2;   // 27557888
  unsigned short* Wt = (unsigned short*)d_ws;
  unsigned short* xp = (unsigned short*)((char*)d_ws + wt_bytes);

  bool fast = (ws_size >= wt_bytes + xp_bytes);
  if (fast) {
    prep_w_kernel<<<72, 256, 0, stream>>>(W, Wt);
    prep_x_kernel<<<BZ * PH, 256, 0, stream>>>(tj, xp);
    spiking_conv_main<<<224, 512, LDS_TOTAL, stream>>>(xp, Wt, Di, out);
    if (hipGetLastError() != hipSuccess) fast = false;  // e.g. LDS-size launch failure
  }
  if (!fast) {
    spiking_conv_fallback<<<100352 / 128, 256, 0, stream>>>(tj, W, Di, out);
  }
}

// Round 5
// 53.480 us; speedup vs baseline: 2.7182x; 1.0920x over previous
//
#include <hip/hip_runtime.h>

// SpikingConv2D: y = conv3x3_same(tj, W) + (1 - D_i[0,f]); out = min(y, 1.0), NHWC fp32.
// R4: patch-resident implicit GEMM. Block = 4 rows x 56 = 224 px, 4 waves, 72 KB LDS
// -> 2 blocks/CU, all 448 blocks co-resident. K = 36 steps (9 taps x 4 quarters of 32ch).
// A quarter double-buffered (2x24KB), B slice TRIPLE-buffered (3x8KB, staged 2 steps
// ahead). Counted vmcnt with 2-step suffix window: nOut(S) = issues(S)+issues(S-1) --
// every load needed at step S is >=2 steps old, hence drained (fixes R3's FIFO race).
// No LDS swizzle: channel-group is the minor dim -> writes (tid-linear) and fragment
// reads (64 consecutive granules) are conflict-free.

#define BZ 32
#define CC 128
#define HH 56
#define WWD 56
#define HWP 3136
#define FF 128
#define PH 58
#define PW 58
#define NSTEP 36
#define AB_BYTES 24576      // per A buffer: 1536 granules * 16 B (1392 real)
#define A_GRAN_REAL 1392    // 6 rows * 58 px * 4 granules
#define BOFF 49152
#define BB_BYTES 8192
#define LDS_TOTAL 73728     // 48 KB A + 24 KB B

typedef __attribute__((ext_vector_type(8))) __bf16 bf16x8;
typedef __attribute__((ext_vector_type(4))) float f32x4;
typedef __attribute__((ext_vector_type(8))) unsigned short us8;
typedef __attribute__((ext_vector_type(4))) float flt4;

__device__ __forceinline__ unsigned short f2bf(float f) {
  unsigned int u = __float_as_uint(f);
  unsigned int r = (u + 0x7FFFu + ((u >> 16) & 1u)) >> 16;
  return (unsigned short)r;
}

#define GLOAD_LDS16(g, l)                                                              \
  __builtin_amdgcn_global_load_lds((const __attribute__((address_space(1))) void*)(g), \
                                   (__attribute__((address_space(3))) void*)(l), 16, 0, 0)

// ---- W repack: W[(c*9+r)][f] f32 -> Wt slice S=q*9+r, granule g=f*4+kg holds
//      channels q*32+kg*8..+8 of filter f, tap r (linear, no swizzle). ----
__global__ void prep_w_kernel(const float* __restrict__ W, unsigned short* __restrict__ Wt) {
  int idx = blockIdx.x * 256 + threadIdx.x;
  if (idx >= NSTEP * 512) return;
  int qr = idx >> 9;
  int g = idx & 511;
  int q = qr / 9, r = qr - q * 9;
  int f = g >> 2, kg = g & 3;
  us8 v;
#pragma unroll
  for (int j = 0; j < 8; ++j) {
    int c = q * 32 + kg * 8 + j;
    v[j] = f2bf(W[(c * 9 + r) * FF + f]);
  }
  *reinterpret_cast<us8*>(Wt + (size_t)idx * 8) = v;
}

// ---- image prepass: x NCHW f32 -> xp padded NHWC bf16 [B][58][58][128] ----
__global__ __launch_bounds__(256) void prep_x_kernel(const float* __restrict__ x,
                                                     unsigned short* __restrict__ xp) {
  const int blk = blockIdx.x;
  const int b = blk / PH;
  const int ph = blk - b * PH;
  const int tid = threadIdx.x;
  unsigned short* dst = xp + (size_t)(b * PH + ph) * PW * CC;

  if (ph == 0 || ph == PH - 1) {
    us8 z;
#pragma unroll
    for (int k = 0; k < 8; ++k) z[k] = 0;
    for (int i = tid; i < PW * CC / 8; i += 256) reinterpret_cast<us8*>(dst)[i] = z;
    return;
  }

  __shared__ float sm[CC][57];
  const int h = ph - 1;
  {
    const int c = tid >> 1;
    const int half = tid & 1;
    const float* src = x + ((size_t)(b * CC + c)) * HWP + h * WWD + half * 28;
#pragma unroll
    for (int k = 0; k < 7; ++k) {
      flt4 v = *reinterpret_cast<const flt4*>(src + k * 4);
      sm[c][half * 28 + k * 4 + 0] = v[0];
      sm[c][half * 28 + k * 4 + 1] = v[1];
      sm[c][half * 28 + k * 4 + 2] = v[2];
      sm[c][half * 28 + k * 4 + 3] = v[3];
    }
  }
  __syncthreads();
  for (int i = tid; i < PW * 16; i += 256) {
    const int ww = i >> 4;
    const int cg = i & 15;
    us8 v;
    if (ww == 0 || ww == PW - 1) {
#pragma unroll
      for (int k = 0; k < 8; ++k) v[k] = 0;
    } else {
      const int w = ww - 1;
#pragma unroll
      for (int k = 0; k < 8; ++k) v[k] = f2bf(sm[cg * 8 + k][w]);
    }
    reinterpret_cast<us8*>(dst)[i] = v;
  }
}

// ---------------- main kernel ----------------
struct Ctx {
  const unsigned short* xp;
  const unsigned short* Wt;
  int tid;
  int srcA[6];    // xp element offsets per A chunk (quarter-0 channel base)
  int gbase[7];   // A-frag granule (dh=dw=0) per M-frag
  int bOffB[4];   // B-frag byte offsets within one slice buffer
  f32x4 acc[7][4];
};

// issues(S): A chunk (1) at q<3 && r<6; B slice S+2 (2 loads) at S<=33.
template <int S>
__device__ __forceinline__ void step(Ctx& c, unsigned char* lds) {
  constexpr int q = S / 9, r = S - q * 9;
  constexpr int dh = r / 3 - 1, dw = r - (r / 3) * 3 - 1;
  constexpr int tapoff = (dh * PW + dw) * 4;  // granules
  constexpr bool issueA = (q < 3) && (r < 6);
  constexpr bool issueB = (S <= NSTEP - 3);
  constexpr int aS = issueA ? 1 : 0;
  constexpr int bS = issueB ? 2 : 0;
  constexpr int aP = (S == 0) ? 0 : ((((S - 1) / 9) < 3 && ((S - 1) % 9) < 6) ? 1 : 0);
  constexpr int bP = (S == 0) ? 2 : (((S - 1) <= NSTEP - 3) ? 2 : 0);
  constexpr int nOut = aS + bS + aP + bP;  // 2-step suffix window

  if constexpr (issueA) {  // chunk r of quarter q+1 -> parity (q+1)&1
    const unsigned short* src = c.xp + c.srcA[r] + (q + 1) * 32;
    unsigned char* dst = lds + ((q + 1) & 1) * AB_BYTES + (size_t)(r * 256 + c.tid) * 16;
    GLOAD_LDS16(src, dst);
  }
  if constexpr (issueB) {  // slice S+2 -> buf (S+2)%3, 8 KB in 2 rounds
    const unsigned short* src = c.Wt + (size_t)(S + 2) * 4096 + c.tid * 8;
    unsigned char* dst = lds + BOFF + ((S + 2) % 3) * BB_BYTES + (size_t)c.tid * 16;
    GLOAD_LDS16(src, dst);
    GLOAD_LDS16(src + 2048, dst + 4096);
  }
  asm volatile("s_waitcnt vmcnt(%0)" ::"n"(nOut));
  __builtin_amdgcn_s_barrier();
  __builtin_amdgcn_sched_barrier(0);

  const unsigned char* pa = lds + (q & 1) * AB_BYTES;
  const unsigned char* pb = lds + BOFF + (S % 3) * BB_BYTES;
  bf16x8 af[7], bf[4];
#pragma unroll
  for (int i = 0; i < 7; ++i)
    af[i] = *reinterpret_cast<const bf16x8*>(pa + ((c.gbase[i] + tapoff) << 4));
#pragma unroll
  for (int j = 0; j < 4; ++j)
    bf[j] = *reinterpret_cast<const bf16x8*>(pb + c.bOffB[j]);

  __builtin_amdgcn_s_setprio(1);
#pragma unroll
  for (int i = 0; i < 7; ++i)
#pragma unroll
    for (int j = 0; j < 4; ++j)
      c.acc[i][j] = __builtin_amdgcn_mfma_f32_16x16x32_bf16(af[i], bf[j], c.acc[i][j], 0, 0, 0);
  __builtin_amdgcn_s_setprio(0);
  __builtin_amdgcn_sched_barrier(0);
  __builtin_amdgcn_s_barrier();
}

template <int S>
__device__ __forceinline__ void do_steps(Ctx& c, unsigned char* lds) {
  step<S>(c, lds);
  if constexpr (S + 1 < NSTEP) do_steps<S + 1>(c, lds);
}

__global__ __launch_bounds__(256, 2) void spiking_conv_main(
    const unsigned short* __restrict__ xp, const unsigned short* __restrict__ Wt,
    const float* __restrict__ Di, float* __restrict__ out) {
  extern __shared__ unsigned char lds[];

  const int bid = blockIdx.x;
  const int wg = (bid & 7) * 56 + (bid >> 3);  // 448 = 56 per XCD, bijective
  const int b = wg / 14;
  const int rg = wg - b * 14;
  const int h0 = rg * 4;

  Ctx c;
  c.xp = xp;
  c.Wt = Wt;
  const int tid = threadIdx.x;
  c.tid = tid;
  const int lane = tid & 63, wv = tid >> 6;
  const int wr = wv >> 1, wc = wv & 1;
  const int frow = lane & 15, kg = lane >> 4;

#pragma unroll
  for (int k = 0; k < 6; ++k) {
    int g = k * 256 + tid;
    if (g >= A_GRAN_REAL) g = 0;  // pad granule: harmless in-bounds source
    int prow = g / 232;           // patch row (58 px * 4 granules)
    int rem = g - prow * 232;
    int px = rem >> 2;
    int kg2 = rem & 3;
    c.srcA[k] = ((b * PH + h0 + prow) * PW + px) * CC + kg2 * 8;
  }
#pragma unroll
  for (int i = 0; i < 7; ++i) {
    int t = 16 * i + frow;  // 0..111 within wave's 112-px half
    int rowb = (t >= 56) ? 1 : 0;
    int col = t - 56 * rowb;
    c.gbase[i] = ((2 * wr + rowb + 1) * PW + (col + 1)) * 4 + kg;
  }
#pragma unroll
  for (int j = 0; j < 4; ++j)
    c.bOffB[j] = ((wc * 64 + 16 * j + frow) * 4 + kg) << 4;

  const f32x4 zero = {0.0f, 0.0f, 0.0f, 0.0f};
#pragma unroll
  for (int i = 0; i < 7; ++i)
#pragma unroll
    for (int j = 0; j < 4; ++j) c.acc[i][j] = zero;

  // prologue: A quarter 0 (parity 0), B slice 0 -> buf0, B slice 1 -> buf1.
  // No wait/barrier here: step 0's suffix-window wait (nOut=5) drains A q0 + B s0
  // while keeping B s1 and step-0 issues in flight.
#pragma unroll
  for (int k = 0; k < 6; ++k)
    GLOAD_LDS16(xp + c.srcA[k], lds + (size_t)(k * 256 + tid) * 16);
  GLOAD_LDS16(Wt + tid * 8, lds + BOFF + (size_t)tid * 16);
  GLOAD_LDS16(Wt + 2048 + tid * 8, lds + BOFF + 4096 + (size_t)tid * 16);
  GLOAD_LDS16(Wt + 4096 + tid * 8, lds + BOFF + BB_BYTES + (size_t)tid * 16);
  GLOAD_LDS16(Wt + 6144 + tid * 8, lds + BOFF + BB_BYTES + 4096 + (size_t)tid * 16);

  do_steps<0>(c, lds);

  // epilogue: + (1 - D_i[f]), clamp 1.0, NHWC fp32
#pragma unroll
  for (int j = 0; j < 4; ++j) {
    const int col = wc * 64 + 16 * j + frow;
    const float thr = 1.0f - Di[col];
#pragma unroll
    for (int i = 0; i < 7; ++i) {
      const int bt = 16 * i + kg * 4;  // 4-run never crosses the 56 boundary
      const int rowb = (bt >= 56) ? 1 : 0;
      const int wl0 = bt - 56 * rowb;
      const int orow = h0 + 2 * wr + rowb;
      const size_t obase = ((size_t)b * HWP + (size_t)orow * WWD + wl0) * FF + col;
#pragma unroll
      for (int qq = 0; qq < 4; ++qq) {
        float v = c.acc[i][j][qq] + thr;
        out[obase + (size_t)qq * FF] = fminf(v, 1.0f);
      }
    }
  }
}

// ---- fallback (round-0 style, reads W directly) ----
__global__ __launch_bounds__(256) void spiking_conv_fallback(
    const float* __restrict__ x, const float* __restrict__ Wf,
    const float* __restrict__ Di, float* __restrict__ out) {
  __shared__ unsigned short Asm2[128][32];
  __shared__ unsigned short Bsm2[128][32];
  const int tid = threadIdx.x;
  const int m0 = blockIdx.x * 128;
  const int mi = tid & 127;
  const int half = tid >> 7;
  const int m = m0 + mi;
  const int bimg = m / HWP;
  const int p = m - bimg * HWP;
  const int h = p / WWD;
  const int w = p - h * WWD;
  const int baseA = (bimg * CC) * HWP + h * WWD + w;
  const int lane = tid & 63;
  const int wid = tid >> 6;
  const int wr = wid >> 1;
  const int wc = wid & 1;
  const int frow = lane & 15;
  const int kg = lane >> 4;
  f32x4 acc[4][4];
  const f32x4 zero = {0.0f, 0.0f, 0.0f, 0.0f};
#pragma unroll
  for (int i = 0; i < 4; ++i)
#pragma unroll
    for (int j = 0; j < 4; ++j) acc[i][j] = zero;
  for (int r = 0; r < 9; ++r) {
    const int dh = r / 3 - 1;
    const int dw = r - (r / 3) * 3 - 1;
    const int hh = h + dh;
    const int ww2 = w + dw;
    const bool valid = ((unsigned)hh < (unsigned)HH) && ((unsigned)ww2 < (unsigned)WWD);
    const int aoff2 = baseA + dh * WWD + dw + half * 16 * HWP;
    for (int c0 = 0; c0 < CC; c0 += 32) {
      __syncthreads();
      {
        const float* src = x + aoff2 + c0 * HWP;
        us8 v0, v1;
#pragma unroll
        for (int i = 0; i < 8; ++i) {
          float f0 = valid ? src[i * HWP] : 0.0f;
          float f1 = valid ? src[(i + 8) * HWP] : 0.0f;
          v0[i] = f2bf(f0);
          v1[i] = f2bf(f1);
        }
        *reinterpret_cast<us8*>(&Asm2[mi][half * 16]) = v0;
        *reinterpret_cast<us8*>(&Asm2[mi][half * 16 + 8]) = v1;
      }
      {
        us8 v0, v1;
#pragma unroll
        for (int i = 0; i < 8; ++i) {
          int cc2 = c0 + half * 16 + i;
          v0[i] = f2bf(Wf[(cc2 * 9 + r) * FF + mi]);
          v1[i] = f2bf(Wf[((cc2 + 8) * 9 + r) * FF + mi]);
        }
        *reinterpret_cast<us8*>(&Bsm2[mi][half * 16]) = v0;
        *reinterpret_cast<us8*>(&Bsm2[mi][half * 16 + 8]) = v1;
      }
      __syncthreads();
      bf16x8 af[4], bfr[4];
#pragma unroll
      for (int i = 0; i < 4; ++i)
        af[i] = *reinterpret_cast<const bf16x8*>(&Asm2[wr * 64 + i * 16 + frow][kg * 8]);
#pragma unroll
      for (int j = 0; j < 4; ++j)
        bfr[j] = *reinterpret_cast<const bf16x8*>(&Bsm2[wc * 64 + j * 16 + frow][kg * 8]);
#pragma unroll
      for (int i = 0; i < 4; ++i)
#pragma unroll
        for (int j = 0; j < 4; ++j)
          acc[i][j] = __builtin_amdgcn_mfma_f32_16x16x32_bf16(af[i], bfr[j], acc[i][j], 0, 0, 0);
    }
  }
#pragma unroll
  for (int j = 0; j < 4; ++j) {
    const int col = wc * 64 + j * 16 + frow;
    const float thr = 1.0f - Di[col];
#pragma unroll
    for (int i = 0; i < 4; ++i) {
      const int rbase = m0 + wr * 64 + i * 16 + kg * 4;
#pragma unroll
      for (int qq = 0; qq < 4; ++qq) {
        float v = acc[i][j][qq] + thr;
        out[(size_t)(rbase + qq) * FF + col] = fminf(v, 1.0f);
      }
    }
  }
}

extern "C" void kernel_launch(void* const* d_in, const int* in_sizes, int n_in,
                              void* d_out, int out_size, void* d_ws, size_t ws_size,
                              hipStream_t stream) {
  const float* tj = (const float*)d_in[0];
  const float* W = (const float*)d_in[1];
  const float* Di = (const float*)d_in[2];
  float* out = (float*)d_out;

  const size_t wt_bytes = (size_t)NSTEP * 512 * 16;        // 294912
  const size_t xp_bytes = (size_t)BZ * PH * PW * CC * 2;   // 27557888
  unsigned short* Wt = (unsigned short*)d_ws;
  unsigned short* xp = (unsigned short*)((char*)d_ws + wt_bytes);

  bool fast = (ws_size >= wt_bytes + xp_bytes);
  if (fast) {
    prep_w_kernel<<<72, 256, 0, stream>>>(W, Wt);
    prep_x_kernel<<<BZ * PH, 256, 0, stream>>>(tj, xp);
    spiking_conv_main<<<448, 256, LDS_TOTAL, stream>>>(xp, Wt, Di, out);
    if (hipGetLastError() != hipSuccess) fast = false;
  }
  if (!fast) {
    spiking_conv_fallback<<<100352 / 128, 256, 0, stream>>>(tj, W, Di, out);
  }
}